// Round 1
// baseline (186.595 us; speedup 1.0000x reference)
//
#include <hip/hip_runtime.h>

#define BB 8
#define SS 256
#define CHAR_E 128
#define BI_E 64
#define EMBED 256
#define HH 256
#define NTAGS 17
#define SPAD 260  // S + 2 zero-pad rows each side

__device__ __forceinline__ float fast_rcp(float x) {
    return __builtin_amdgcn_rcpf(x);
}
__device__ __forceinline__ float fast_sigmoid(float x) {
    return fast_rcp(1.0f + __expf(-x));
}
__device__ __forceinline__ float fast_tanh(float x) {
    // tanh(x) = 1 - 2/(exp(2x)+1); saturates correctly at +-inf
    float e = __expf(2.0f * x);
    return 1.0f - 2.0f * fast_rcp(e + 1.0f);
}

// ---------------- embedding gather -> padded x [B][SPAD][EMBED] -------------
__global__ __launch_bounds__(256) void embed_kernel(
        const int* __restrict__ tokens,
        const float* __restrict__ char_emb,
        const float* __restrict__ bigram_emb,
        float* __restrict__ xpad) {
    int blk = blockIdx.x;            // b*SPAD + r
    int b = blk / SPAD, r = blk % SPAD;
    int e = threadIdx.x;
    float v = 0.0f;
    if (r >= 2 && r < SS + 2) {
        int s = r - 2;
        const int* tk = tokens + (b * SS + s) * 3;
        if (e < CHAR_E)              v = char_emb[tk[0] * CHAR_E + e];
        else if (e < CHAR_E + BI_E)  v = bigram_emb[tk[1] * BI_E + (e - CHAR_E)];
        else                         v = bigram_emb[tk[2] * BI_E + (e - CHAR_E - BI_E)];
    }
    xpad[blk * EMBED + e] = v;
}

// -------- conv1/3/5 + bias + tanh + elementwise max -> c [B][S][H] ----------
// block = (b, s-tile of 8); threads = h. x reads are block-uniform (scalar
// pipe); weight reads coalesced over h. 72 FMA per e-iter per thread.
__global__ __launch_bounds__(256) void conv_kernel(
        const float* __restrict__ xpad,
        const float* __restrict__ w1, const float* __restrict__ b1,
        const float* __restrict__ w3, const float* __restrict__ b3,
        const float* __restrict__ w5, const float* __restrict__ b5,
        float* __restrict__ c) {
    int blk = blockIdx.x;            // b*(S/8) + sblk
    int b = blk >> 5;                // S/8 = 32
    int s0 = (blk & 31) << 3;
    int h = threadIdx.x;

    float acc5[8], acc3[8], acc1[8];
    #pragma unroll
    for (int s = 0; s < 8; ++s) { acc5[s] = 0.f; acc3[s] = 0.f; acc1[s] = 0.f; }

    #pragma unroll 2
    for (int e = 0; e < EMBED; ++e) {
        float xv[12];
        #pragma unroll
        for (int r = 0; r < 12; ++r)
            xv[r] = xpad[(b * SPAD + s0 + r) * EMBED + e];   // uniform -> s_load
        float w5v[5], w3v[3], w1v;
        #pragma unroll
        for (int k = 0; k < 5; ++k) w5v[k] = w5[(k * EMBED + e) * HH + h];
        #pragma unroll
        for (int k = 0; k < 3; ++k) w3v[k] = w3[(k * EMBED + e) * HH + h];
        w1v = w1[e * HH + h];
        #pragma unroll
        for (int s = 0; s < 8; ++s) {
            #pragma unroll
            for (int k = 0; k < 5; ++k) acc5[s] = fmaf(xv[s + k], w5v[k], acc5[s]);
            #pragma unroll
            for (int k = 0; k < 3; ++k) acc3[s] = fmaf(xv[s + k + 1], w3v[k], acc3[s]);
            acc1[s] = fmaf(xv[s + 2], w1v, acc1[s]);
        }
    }
    float bb1 = b1[h], bb3 = b3[h], bb5 = b5[h];
    #pragma unroll
    for (int s = 0; s < 8; ++s) {
        float t1 = fast_tanh(acc1[s] + bb1);
        float t3 = fast_tanh(acc3[s] + bb3);
        float t5 = fast_tanh(acc5[s] + bb5);
        c[(b * SS + s0 + s) * HH + h] = fmaxf(t1, fmaxf(t3, t5));
    }
}

// -------------------- g0 = c@W0+b0, g1 = c@W1+b1 ----------------------------
__global__ __launch_bounds__(256) void gemm_g_kernel(
        const float* __restrict__ c,
        const float* __restrict__ W0, const float* __restrict__ b0,
        const float* __restrict__ W1, const float* __restrict__ b1,
        float* __restrict__ g0, float* __restrict__ g1) {
    int blk = blockIdx.x;            // b*(S/8) + iblk
    int b = blk >> 5;
    int i0 = (blk & 31) << 3;
    int h = threadIdx.x;
    float a0[8], a1[8];
    #pragma unroll
    for (int s = 0; s < 8; ++s) { a0[s] = 0.f; a1[s] = 0.f; }

    #pragma unroll 2
    for (int e = 0; e < HH; ++e) {
        float w0v = W0[e * HH + h];
        float w1v = W1[e * HH + h];
        #pragma unroll
        for (int s = 0; s < 8; ++s) {
            float cv = c[(b * SS + i0 + s) * HH + e];        // uniform -> s_load
            a0[s] = fmaf(cv, w0v, a0[s]);
            a1[s] = fmaf(cv, w1v, a1[s]);
        }
    }
    float bb0 = b0[h], bb1 = b1[h];
    #pragma unroll
    for (int s = 0; s < 8; ++s) {
        g0[(b * SS + i0 + s) * HH + h] = a0[s] + bb0;
        g1[(b * SS + i0 + s) * HH + h] = a1[s] + bb1;
    }
}

// ------ relation layer + tanh + output projection + softmax -----------------
// block = (b, 4 i's); threads = h. Each j-iter: 2 coalesced loads reused
// across 4 i's; 4 sigmoid+fma. Epilogue does rel@Wo+bo and softmax in-block.
__global__ __launch_bounds__(256) void relation_kernel(
        const float* __restrict__ c, const float* __restrict__ g0,
        const float* __restrict__ g1, const int* __restrict__ masks,
        const float* __restrict__ Wo, const float* __restrict__ bo,
        float* __restrict__ out) {
    constexpr int IT = 4;
    int blk = blockIdx.x;            // b*(S/IT) + iblk
    int b = blk >> 6;                // S/IT = 64
    int i0 = (blk & 63) * IT;
    int tid = threadIdx.x;
    int h = tid;

    __shared__ float sred[4];
    __shared__ float rel_lds[IT][HH];
    __shared__ float lg[IT][NTAGS];

    // lengths[b] = sum_j m[b,j]
    float lm = (float)masks[b * SS + tid];
    #pragma unroll
    for (int o = 32; o; o >>= 1) lm += __shfl_xor(lm, o);
    if ((tid & 63) == 0) sred[tid >> 6] = lm;
    __syncthreads();
    float Linv = fast_rcp(sred[0] + sred[1] + sred[2] + sred[3]);

    float g0t[IT], acc[IT];
    #pragma unroll
    for (int t = 0; t < IT; ++t) {
        g0t[t] = g0[(b * SS + i0 + t) * HH + h];
        acc[t] = 0.f;
    }

    for (int j = 0; j < SS; ++j) {
        float mj = (float)masks[b * SS + j];                 // uniform
        float g1v = g1[(b * SS + j) * HH + h];
        float cv = c[(b * SS + j) * HH + h] * mj;
        #pragma unroll
        for (int t = 0; t < IT; ++t) {
            float sg = fast_sigmoid(g0t[t] + g1v);
            acc[t] = fmaf(sg, cv, acc[t]);
        }
    }

    #pragma unroll
    for (int t = 0; t < IT; ++t) {
        float mi = (float)masks[b * SS + i0 + t];
        rel_lds[t][h] = fast_tanh(acc[t] * Linv * mi);
    }
    __syncthreads();

    // logits: 4 groups of 64 lanes, lanes 0..16 each compute one tag's dot
    int grp = tid >> 6, lane = tid & 63;
    if (lane < NTAGS) {
        float lacc = bo[lane];
        for (int hh = 0; hh < HH; ++hh)
            lacc = fmaf(rel_lds[grp][hh], Wo[hh * NTAGS + lane], lacc);
        lg[grp][lane] = lacc;
    }
    __syncthreads();

    // softmax over 17 tags, one thread per i
    if (tid < IT) {
        float mx = -1e30f;
        #pragma unroll
        for (int t = 0; t < NTAGS; ++t) mx = fmaxf(mx, lg[tid][t]);
        float ex[NTAGS], sum = 0.f;
        #pragma unroll
        for (int t = 0; t < NTAGS; ++t) { ex[t] = __expf(lg[tid][t] - mx); sum += ex[t]; }
        float si = fast_rcp(sum);
        int i = i0 + tid;
        #pragma unroll
        for (int t = 0; t < NTAGS; ++t)
            out[(b * SS + i) * NTAGS + t] = ex[t] * si;
    }
}

extern "C" void kernel_launch(void* const* d_in, const int* in_sizes, int n_in,
                              void* d_out, int out_size, void* d_ws, size_t ws_size,
                              hipStream_t stream) {
    const int*   tokens     = (const int*)d_in[0];
    const int*   masks      = (const int*)d_in[1];
    const float* char_emb   = (const float*)d_in[2];
    const float* bigram_emb = (const float*)d_in[3];
    const float* conv1_w    = (const float*)d_in[4];
    const float* conv1_b    = (const float*)d_in[5];
    const float* conv3_w    = (const float*)d_in[6];
    const float* conv3_b    = (const float*)d_in[7];
    const float* conv5_w    = (const float*)d_in[8];
    const float* conv5_b    = (const float*)d_in[9];
    const float* W0         = (const float*)d_in[10];
    const float* b0         = (const float*)d_in[11];
    const float* W1         = (const float*)d_in[12];
    const float* b1         = (const float*)d_in[13];
    const float* Wo         = (const float*)d_in[14];
    const float* bo         = (const float*)d_in[15];
    float* out = (float*)d_out;

    float* ws   = (float*)d_ws;
    float* xpad = ws;                                   // B*SPAD*EMBED = 532480
    float* c    = xpad + BB * SPAD * EMBED;             // B*S*H = 524288
    float* g0   = c + BB * SS * HH;
    float* g1   = g0 + BB * SS * HH;                    // total ~8.4 MB

    embed_kernel<<<BB * SPAD, 256, 0, stream>>>(tokens, char_emb, bigram_emb, xpad);
    conv_kernel<<<BB * (SS / 8), 256, 0, stream>>>(xpad, conv1_w, conv1_b,
                                                   conv3_w, conv3_b,
                                                   conv5_w, conv5_b, c);
    gemm_g_kernel<<<BB * (SS / 8), 256, 0, stream>>>(c, W0, b0, W1, b1, g0, g1);
    relation_kernel<<<BB * (SS / 4), 256, 0, stream>>>(c, g0, g1, masks, Wo, bo, out);
}

// Round 2
// 121.084 us; speedup vs baseline: 1.5410x; 1.5410x over previous
//
#include <hip/hip_runtime.h>
#include <hip/hip_bf16.h>

#define BB 8
#define SS 256
#define CHAR_E 128
#define BI_E 64
#define EMBED 256
#define HH 256
#define NTAGS 17
#define SPAD 260  // S + 2 zero-pad rows each side

typedef __attribute__((ext_vector_type(8))) short short8;
typedef __attribute__((ext_vector_type(4))) float f32x4;
#define MFMA16(a, b, c) __builtin_amdgcn_mfma_f32_16x16x32_bf16(a, b, c, 0, 0, 0)

__device__ __forceinline__ float fast_rcp(float x) {
    return __builtin_amdgcn_rcpf(x);
}
__device__ __forceinline__ float fast_sigmoid(float x) {
    return fast_rcp(1.0f + __expf(-x));
}
__device__ __forceinline__ float fast_tanh(float x) {
    float e = __expf(2.0f * x);
    return 1.0f - 2.0f * fast_rcp(e + 1.0f);
}

// ---------------- embedding gather -> padded bf16 x [B][SPAD][EMBED] --------
__global__ __launch_bounds__(256) void embed_kernel(
        const int* __restrict__ tokens,
        const float* __restrict__ char_emb,
        const float* __restrict__ bigram_emb,
        __hip_bfloat16* __restrict__ xbf) {
    int blk = blockIdx.x;            // b*SPAD + r
    int b = blk / SPAD, r = blk % SPAD;
    int e = threadIdx.x;
    float v = 0.0f;
    if (r >= 2 && r < SS + 2) {
        int s = r - 2;
        const int* tk = tokens + (b * SS + s) * 3;
        if (e < CHAR_E)              v = char_emb[tk[0] * CHAR_E + e];
        else if (e < CHAR_E + BI_E)  v = bigram_emb[tk[1] * BI_E + (e - CHAR_E)];
        else                         v = bigram_emb[tk[2] * BI_E + (e - CHAR_E - BI_E)];
    }
    xbf[blk * EMBED + e] = __float2bfloat16(v);
}

// ------- pack weights: WcombT [768][1280] bf16, W01T [512][256] bf16 --------
// WcombT row n (output col), cols kk = tap*256+e. n<256: conv5 (all 5 taps);
// n in [256,512): conv3 at taps 1..3; n>=512: conv1 at tap 2. Zeros elsewhere.
__global__ __launch_bounds__(256) void pack_w_kernel(
        const float* __restrict__ w1, const float* __restrict__ w3,
        const float* __restrict__ w5,
        const float* __restrict__ W0, const float* __restrict__ W1mat,
        __hip_bfloat16* __restrict__ WcombT, __hip_bfloat16* __restrict__ W01T) {
    int blk = blockIdx.x;
    int t = threadIdx.x;
    if (blk < 768) {
        int n = blk;
        int h = n & 255;
        int scale = n >> 8;          // 0: conv5, 1: conv3, 2: conv1
        for (int kk = t; kk < 1280; kk += 256) {
            int k = kk >> 8;         // tap 0..4
            int e = kk & 255;
            float v = 0.f;
            if (scale == 0)      v = w5[(k * EMBED + e) * HH + h];
            else if (scale == 1) { if (k >= 1 && k <= 3) v = w3[((k - 1) * EMBED + e) * HH + h]; }
            else                 { if (k == 2) v = w1[e * HH + h]; }
            WcombT[n * 1280 + kk] = __float2bfloat16(v);
        }
    } else {
        int n = blk - 768;           // 0..511
        int e = t;
        float v = (n < 256) ? W0[e * HH + n] : W1mat[e * HH + (n - 256)];
        W01T[n * 256 + e] = __float2bfloat16(v);
    }
}

// ------------- conv as MFMA GEMM: M=2048, K=1280, N=768 ---------------------
// A row i=(b,s) is the contiguous slice xbf[(b*SPAD+s)*256 .. +1280) (5-tap
// im2col window = 5 consecutive padded rows). B = WcombT (pre-transposed).
__global__ __launch_bounds__(256) void conv_mfma_kernel(
        const __hip_bfloat16* __restrict__ xbf,
        const __hip_bfloat16* __restrict__ WcombT,
        float* __restrict__ y) {
    int blk = blockIdx.x;            // 32 m-tiles * 12 n-tiles = 384
    int by = blk / 12, bx = blk % 12;
    int tid = threadIdx.x;
    int w = tid >> 6, lane = tid & 63;
    int wr = w >> 1, wc = w & 1;
    int m0 = by * 64 + wr * 32;
    int n0 = bx * 64 + wc * 32;
    int fr = lane & 15, fq = lane >> 4;

    const short8* aptr[2];
    const short8* bptr[2];
    #pragma unroll
    for (int m = 0; m < 2; ++m) {
        int i = m0 + m * 16 + fr;
        int b = i >> 8, s = i & 255;
        aptr[m] = (const short8*)(xbf + (b * SPAD + s) * EMBED + fq * 8);
    }
    #pragma unroll
    for (int n = 0; n < 2; ++n) {
        int cidx = n0 + n * 16 + fr;
        bptr[n] = (const short8*)(WcombT + cidx * 1280 + fq * 8);
    }

    f32x4 acc[2][2] = {};
    for (int ks = 0; ks < 40; ++ks) {
        short8 a0 = aptr[0][ks * 4];     // ks*32 elems = ks*4 short8
        short8 a1 = aptr[1][ks * 4];
        short8 b0 = bptr[0][ks * 4];
        short8 b1 = bptr[1][ks * 4];
        acc[0][0] = MFMA16(a0, b0, acc[0][0]);
        acc[0][1] = MFMA16(a0, b1, acc[0][1]);
        acc[1][0] = MFMA16(a1, b0, acc[1][0]);
        acc[1][1] = MFMA16(a1, b1, acc[1][1]);
    }
    #pragma unroll
    for (int m = 0; m < 2; ++m)
        #pragma unroll
        for (int n = 0; n < 2; ++n) {
            int col = n0 + n * 16 + fr;
            #pragma unroll
            for (int j = 0; j < 4; ++j) {
                int row = m0 + m * 16 + fq * 4 + j;
                y[row * 768 + col] = acc[m][n][j];
            }
        }
}

// ------- conv epilogue: bias + tanh + max over scales -> c f32 + bf16 -------
__global__ __launch_bounds__(256) void conv_epi_kernel(
        const float* __restrict__ y,
        const float* __restrict__ b1, const float* __restrict__ b3,
        const float* __restrict__ b5,
        float* __restrict__ c, __hip_bfloat16* __restrict__ cbf) {
    int i = blockIdx.x;
    int h = threadIdx.x;
    float t5 = fast_tanh(y[i * 768 + h] + b5[h]);
    float t3 = fast_tanh(y[i * 768 + 256 + h] + b3[h]);
    float t1 = fast_tanh(y[i * 768 + 512 + h] + b1[h]);
    float v = fmaxf(t1, fmaxf(t3, t5));
    c[i * HH + h] = v;
    cbf[i * HH + h] = __float2bfloat16(v);
}

// ------------- g0/g1 as MFMA GEMM: M=2048, K=256, N=512 ---------------------
__global__ __launch_bounds__(256) void gemm_g_mfma_kernel(
        const __hip_bfloat16* __restrict__ cbf,
        const __hip_bfloat16* __restrict__ W01T,
        const float* __restrict__ b0, const float* __restrict__ b1v,
        float* __restrict__ g0, float* __restrict__ g1) {
    int blk = blockIdx.x;            // 32 m-tiles * 8 n-tiles = 256
    int by = blk / 8, bx = blk % 8;
    int tid = threadIdx.x;
    int w = tid >> 6, lane = tid & 63;
    int wr = w >> 1, wc = w & 1;
    int m0 = by * 64 + wr * 32;
    int n0 = bx * 64 + wc * 32;
    int fr = lane & 15, fq = lane >> 4;

    const short8* aptr[2];
    const short8* bptr[2];
    #pragma unroll
    for (int m = 0; m < 2; ++m)
        aptr[m] = (const short8*)(cbf + (m0 + m * 16 + fr) * HH + fq * 8);
    #pragma unroll
    for (int n = 0; n < 2; ++n)
        bptr[n] = (const short8*)(W01T + (n0 + n * 16 + fr) * HH + fq * 8);

    f32x4 acc[2][2] = {};
    for (int ks = 0; ks < 8; ++ks) {
        short8 a0 = aptr[0][ks * 4];
        short8 a1 = aptr[1][ks * 4];
        short8 b0 = bptr[0][ks * 4];
        short8 b1 = bptr[1][ks * 4];
        acc[0][0] = MFMA16(a0, b0, acc[0][0]);
        acc[0][1] = MFMA16(a0, b1, acc[0][1]);
        acc[1][0] = MFMA16(a1, b0, acc[1][0]);
        acc[1][1] = MFMA16(a1, b1, acc[1][1]);
    }
    #pragma unroll
    for (int m = 0; m < 2; ++m)
        #pragma unroll
        for (int n = 0; n < 2; ++n) {
            int col = n0 + n * 16 + fr;
            float bias = (col < 256) ? b0[col] : b1v[col - 256];
            #pragma unroll
            for (int j = 0; j < 4; ++j) {
                int row = m0 + m * 16 + fq * 4 + j;
                float vv = acc[m][n][j] + bias;
                if (col < 256) g0[row * HH + col] = vv;
                else           g1[row * HH + (col - 256)] = vv;
            }
        }
}

// ------ relation layer + tanh + output projection + softmax -----------------
__global__ __launch_bounds__(256) void relation_kernel(
        const float* __restrict__ c, const float* __restrict__ g0,
        const float* __restrict__ g1, const int* __restrict__ masks,
        const float* __restrict__ Wo, const float* __restrict__ bo,
        float* __restrict__ out) {
    constexpr int IT = 4;
    int blk = blockIdx.x;            // b*(S/IT) + iblk
    int b = blk >> 6;                // S/IT = 64
    int i0 = (blk & 63) * IT;
    int tid = threadIdx.x;
    int h = tid;

    __shared__ float sred[4];
    __shared__ float rel_lds[IT][HH];
    __shared__ float lg[IT][NTAGS];

    float lm = (float)masks[b * SS + tid];
    #pragma unroll
    for (int o = 32; o; o >>= 1) lm += __shfl_xor(lm, o);
    if ((tid & 63) == 0) sred[tid >> 6] = lm;
    __syncthreads();
    float Linv = fast_rcp(sred[0] + sred[1] + sred[2] + sred[3]);

    float g0t[IT], acc[IT];
    #pragma unroll
    for (int t = 0; t < IT; ++t) {
        g0t[t] = g0[(b * SS + i0 + t) * HH + h];
        acc[t] = 0.f;
    }

    for (int j = 0; j < SS; ++j) {
        float mj = (float)masks[b * SS + j];
        float g1v = g1[(b * SS + j) * HH + h];
        float cv = c[(b * SS + j) * HH + h] * mj;
        #pragma unroll
        for (int t = 0; t < IT; ++t) {
            float sg = fast_sigmoid(g0t[t] + g1v);
            acc[t] = fmaf(sg, cv, acc[t]);
        }
    }

    #pragma unroll
    for (int t = 0; t < IT; ++t) {
        float mi = (float)masks[b * SS + i0 + t];
        rel_lds[t][h] = fast_tanh(acc[t] * Linv * mi);
    }
    __syncthreads();

    int grp = tid >> 6, lane = tid & 63;
    if (lane < NTAGS) {
        float lacc = bo[lane];
        for (int hh = 0; hh < HH; ++hh)
            lacc = fmaf(rel_lds[grp][hh], Wo[hh * NTAGS + lane], lacc);
        lg[grp][lane] = lacc;
    }
    __syncthreads();

    if (tid < IT) {
        float mx = -1e30f;
        #pragma unroll
        for (int t = 0; t < NTAGS; ++t) mx = fmaxf(mx, lg[tid][t]);
        float ex[NTAGS], sum = 0.f;
        #pragma unroll
        for (int t = 0; t < NTAGS; ++t) { ex[t] = __expf(lg[tid][t] - mx); sum += ex[t]; }
        float si = fast_rcp(sum);
        int i = i0 + tid;
        #pragma unroll
        for (int t = 0; t < NTAGS; ++t)
            out[(b * SS + i) * NTAGS + t] = ex[t] * si;
    }
}

extern "C" void kernel_launch(void* const* d_in, const int* in_sizes, int n_in,
                              void* d_out, int out_size, void* d_ws, size_t ws_size,
                              hipStream_t stream) {
    const int*   tokens     = (const int*)d_in[0];
    const int*   masks      = (const int*)d_in[1];
    const float* char_emb   = (const float*)d_in[2];
    const float* bigram_emb = (const float*)d_in[3];
    const float* conv1_w    = (const float*)d_in[4];
    const float* conv1_b    = (const float*)d_in[5];
    const float* conv3_w    = (const float*)d_in[6];
    const float* conv3_b    = (const float*)d_in[7];
    const float* conv5_w    = (const float*)d_in[8];
    const float* conv5_b    = (const float*)d_in[9];
    const float* W0         = (const float*)d_in[10];
    const float* b0         = (const float*)d_in[11];
    const float* W1         = (const float*)d_in[12];
    const float* b1         = (const float*)d_in[13];
    const float* Wo         = (const float*)d_in[14];
    const float* bo         = (const float*)d_in[15];
    float* out = (float*)d_out;

    char* p = (char*)d_ws;
    __hip_bfloat16* xbf    = (__hip_bfloat16*)p;  p += BB * SPAD * EMBED * 2;   // 1.06 MB
    __hip_bfloat16* WcombT = (__hip_bfloat16*)p;  p += 768 * 1280 * 2;          // 1.97 MB
    __hip_bfloat16* W01T   = (__hip_bfloat16*)p;  p += 512 * 256 * 2;           // 0.26 MB
    __hip_bfloat16* cbf    = (__hip_bfloat16*)p;  p += 2048 * 256 * 2;          // 1.05 MB
    float* yconv = (float*)p;  p += 2048 * 768 * 4;                             // 6.3 MB
    float* c     = (float*)p;  p += 2048 * 256 * 4;                             // 2.1 MB
    float* g0    = (float*)p;  p += 2048 * 256 * 4;
    float* g1    = (float*)p;  p += 2048 * 256 * 4;                             // total ~17 MB

    embed_kernel<<<BB * SPAD, 256, 0, stream>>>(tokens, char_emb, bigram_emb, xbf);
    pack_w_kernel<<<768 + 512, 256, 0, stream>>>(conv1_w, conv3_w, conv5_w,
                                                 W0, W1, WcombT, W01T);
    conv_mfma_kernel<<<32 * 12, 256, 0, stream>>>(xbf, WcombT, yconv);
    conv_epi_kernel<<<2048, 256, 0, stream>>>(yconv, conv1_b, conv3_b, conv5_b, c, cbf);
    gemm_g_mfma_kernel<<<32 * 8, 256, 0, stream>>>(cbf, W01T, b0, b1, g0, g1);
    relation_kernel<<<BB * (SS / 4), 256, 0, stream>>>(c, g0, g1, masks, Wo, bo, out);
}

// Round 3
// 100.666 us; speedup vs baseline: 1.8536x; 1.2028x over previous
//
#include <hip/hip_runtime.h>
#include <hip/hip_bf16.h>

#define BB 8
#define SS 256
#define CHAR_E 128
#define BI_E 64
#define EMBED 256
#define HH 256
#define NTAGS 17
#define SPAD 260   // S + 2 zero-pad rows each side
#define JSPLIT 4
#define ITP 8      // i-rows per relation_part block
#define NLOG2E -1.4426950408889634f

typedef __attribute__((ext_vector_type(8))) short short8;
typedef __attribute__((ext_vector_type(4))) float f32x4;
#define MFMA16(a, b, c) __builtin_amdgcn_mfma_f32_16x16x32_bf16(a, b, c, 0, 0, 0)

__device__ __forceinline__ float fast_rcp(float x) {
    return __builtin_amdgcn_rcpf(x);
}
__device__ __forceinline__ float fast_exp2(float x) {
    return __builtin_amdgcn_exp2f(x);
}
__device__ __forceinline__ float fast_tanh(float x) {
    float e = __expf(2.0f * x);
    return 1.0f - 2.0f * fast_rcp(e + 1.0f);
}

// ---- fused: embedding gather -> xbf, weight packing -> WcombT/W01T ---------
// WcombT interleaved layout: col n = (h>>4)*48 + scale*16 + (h&15);
// rows kk = tap*256 + e. scale 0: conv5 taps 0..4; 1: conv3 taps 1..3; 2: conv1 tap 2.
__global__ __launch_bounds__(256) void embed_pack_kernel(
        const int* __restrict__ tokens,
        const float* __restrict__ char_emb,
        const float* __restrict__ bigram_emb,
        const float* __restrict__ w1, const float* __restrict__ w3,
        const float* __restrict__ w5,
        const float* __restrict__ W0, const float* __restrict__ W1mat,
        __hip_bfloat16* __restrict__ xbf,
        __hip_bfloat16* __restrict__ WcombT,
        __hip_bfloat16* __restrict__ W01T) {
    int blk = blockIdx.x;
    int t = threadIdx.x;
    if (blk < BB * SPAD) {
        int b = blk / SPAD, r = blk % SPAD;
        float v = 0.0f;
        if (r >= 2 && r < SS + 2) {
            int s = r - 2;
            const int* tk = tokens + (b * SS + s) * 3;
            if (t < CHAR_E)              v = char_emb[tk[0] * CHAR_E + t];
            else if (t < CHAR_E + BI_E)  v = bigram_emb[tk[1] * BI_E + (t - CHAR_E)];
            else                         v = bigram_emb[tk[2] * BI_E + (t - CHAR_E - BI_E)];
        }
        xbf[blk * EMBED + t] = __float2bfloat16(v);
    } else {
        int pb = blk - BB * SPAD;        // 0..1279
        if (pb < 768) {
            int n = pb;
            int hc = n / 48, w16 = n % 48;
            int scale = w16 >> 4, hl = w16 & 15;
            int h = hc * 16 + hl;
            for (int kk = t; kk < 1280; kk += 256) {
                int tap = kk >> 8, e = kk & 255;
                float v = 0.f;
                if (scale == 0)      v = w5[(tap * EMBED + e) * HH + h];
                else if (scale == 1) { if (tap >= 1 && tap <= 3) v = w3[((tap - 1) * EMBED + e) * HH + h]; }
                else                 { if (tap == 2) v = w1[e * HH + h]; }
                WcombT[n * 1280 + kk] = __float2bfloat16(v);
            }
        } else {
            int n = pb - 768;            // 0..511
            float v = (n < 256) ? W0[t * HH + n] : W1mat[t * HH + (n - 256)];
            W01T[n * 256 + t] = __float2bfloat16(v);
        }
    }
}

// ---- conv as MFMA GEMM (M=2048,K=1280,N=768) with fused tanh+max epilogue --
// block: m-tile 32 x h-group 32 (2 h-chunks of 16). Warp (wm,wh): m-frag wm,
// h-chunk wh, 3 scale-frags per h-chunk. acc[3] -> tanh+max -> c + cbf.
__global__ __launch_bounds__(256) void conv_mfma_fused(
        const __hip_bfloat16* __restrict__ xbf,
        const __hip_bfloat16* __restrict__ WcombT,
        const float* __restrict__ cb1, const float* __restrict__ cb3,
        const float* __restrict__ cb5,
        float* __restrict__ c, __hip_bfloat16* __restrict__ cbf) {
    int blk = blockIdx.x;            // 64 m-tiles * 8 h-groups = 512
    int mt = blk >> 3, hg = blk & 7;
    int tid = threadIdx.x, w = tid >> 6, lane = tid & 63;
    int wm = w >> 1, wh = w & 1;
    int fr = lane & 15, fq = lane >> 4;
    int row0 = mt * 32 + wm * 16;
    int hc = hg * 2 + wh;            // h-chunk 0..15

    int i = row0 + fr;
    int b = i >> 8, s = i & 255;
    const short8* ap = (const short8*)(xbf + (b * SPAD + s) * EMBED + fq * 8);
    const short8* bp[3];
    #pragma unroll
    for (int sc = 0; sc < 3; ++sc) {
        int n = hc * 48 + sc * 16 + fr;
        bp[sc] = (const short8*)(WcombT + n * 1280 + fq * 8);
    }

    f32x4 acc[3] = {};
    for (int ks = 0; ks < 40; ++ks) {
        short8 a = ap[ks * 4];
        acc[0] = MFMA16(a, bp[0][ks * 4], acc[0]);
        acc[1] = MFMA16(a, bp[1][ks * 4], acc[1]);
        acc[2] = MFMA16(a, bp[2][ks * 4], acc[2]);
    }

    int h = hc * 16 + fr;
    float bb5 = cb5[h], bb3 = cb3[h], bb1 = cb1[h];
    #pragma unroll
    for (int j = 0; j < 4; ++j) {
        int row = row0 + fq * 4 + j;
        float t5 = fast_tanh(acc[0][j] + bb5);
        float t3 = fast_tanh(acc[1][j] + bb3);
        float t1 = fast_tanh(acc[2][j] + bb1);
        float v = fmaxf(t1, fmaxf(t3, t5));
        c[row * HH + h] = v;
        cbf[row * HH + h] = __float2bfloat16(v);
    }
}

// ---- g0/g1 GEMM (M=2048,K=256,N=512); stores -log2e*(v) for sigmoid -------
__global__ __launch_bounds__(256) void gemm_g_mfma_kernel(
        const __hip_bfloat16* __restrict__ cbf,
        const __hip_bfloat16* __restrict__ W01T,
        const float* __restrict__ b0, const float* __restrict__ b1v,
        float* __restrict__ g0n, float* __restrict__ g1n) {
    int blk = blockIdx.x;            // 32 m-tiles * 8 n-tiles = 256
    int by = blk / 8, bx = blk % 8;
    int tid = threadIdx.x;
    int w = tid >> 6, lane = tid & 63;
    int wr = w >> 1, wc = w & 1;
    int m0 = by * 64 + wr * 32;
    int n0 = bx * 64 + wc * 32;
    int fr = lane & 15, fq = lane >> 4;

    const short8* aptr[2];
    const short8* bptr[2];
    #pragma unroll
    for (int m = 0; m < 2; ++m)
        aptr[m] = (const short8*)(cbf + (m0 + m * 16 + fr) * HH + fq * 8);
    #pragma unroll
    for (int n = 0; n < 2; ++n)
        bptr[n] = (const short8*)(W01T + (n0 + n * 16 + fr) * HH + fq * 8);

    f32x4 acc[2][2] = {};
    for (int ks = 0; ks < 8; ++ks) {
        short8 a0 = aptr[0][ks * 4];
        short8 a1 = aptr[1][ks * 4];
        short8 b0f = bptr[0][ks * 4];
        short8 b1f = bptr[1][ks * 4];
        acc[0][0] = MFMA16(a0, b0f, acc[0][0]);
        acc[0][1] = MFMA16(a0, b1f, acc[0][1]);
        acc[1][0] = MFMA16(a1, b0f, acc[1][0]);
        acc[1][1] = MFMA16(a1, b1f, acc[1][1]);
    }
    #pragma unroll
    for (int m = 0; m < 2; ++m)
        #pragma unroll
        for (int n = 0; n < 2; ++n) {
            int col = n0 + n * 16 + fr;
            float bias = (col < 256) ? b0[col] : b1v[col - 256];
            #pragma unroll
            for (int j = 0; j < 4; ++j) {
                int row = m0 + m * 16 + fq * 4 + j;
                float sv = NLOG2E * (acc[m][n][j] + bias);
                if (col < 256) g0n[row * HH + col] = sv;
                else           g1n[row * HH + (col - 256)] = sv;
            }
        }
}

// ---- relation partial: acc over one j-chunk of 64, ITP=8 rows per block ----
// sigmoid(g0+g1) = rcp(1 + exp2(g0n+g1n)) with g stored pre-scaled by -log2e.
__global__ __launch_bounds__(256) void relation_part_kernel(
        const float* __restrict__ c, const float* __restrict__ g0n,
        const float* __restrict__ g1n, const int* __restrict__ masks,
        float* __restrict__ part) {
    int blk = blockIdx.x;            // jc*256 + b*32 + iblk
    int jc = blk >> 8;
    int rem = blk & 255;
    int b = rem >> 5;
    int i0 = (rem & 31) * ITP;
    int h = threadIdx.x;

    float g0t[ITP], acc[ITP];
    #pragma unroll
    for (int t = 0; t < ITP; ++t) {
        g0t[t] = g0n[(b * SS + i0 + t) * HH + h];
        acc[t] = 0.f;
    }

    int j0 = jc * (SS / JSPLIT);
    for (int jj = 0; jj < SS / JSPLIT; ++jj) {
        int j = j0 + jj;
        float mj = (float)masks[b * SS + j];
        float g1v = g1n[(b * SS + j) * HH + h];
        float cv = c[(b * SS + j) * HH + h] * mj;
        #pragma unroll
        for (int t = 0; t < ITP; ++t) {
            float e = fast_exp2(g0t[t] + g1v);
            acc[t] = fmaf(fast_rcp(1.0f + e), cv, acc[t]);
        }
    }
    #pragma unroll
    for (int t = 0; t < ITP; ++t)
        part[((jc * BB + b) * SS + i0 + t) * HH + h] = acc[t];
}

// ---- relation final: reduce partials + tanh + projection + softmax ---------
__global__ __launch_bounds__(256) void relation_final_kernel(
        const float* __restrict__ part, const int* __restrict__ masks,
        const float* __restrict__ Wo, const float* __restrict__ bo,
        float* __restrict__ out) {
    int blk = blockIdx.x;            // b*64 + iblk
    int b = blk >> 6;
    int i0 = (blk & 63) * 4;
    int tid = threadIdx.x;
    int h = tid;

    __shared__ float sred[4];
    __shared__ float rel_lds[4][HH];
    __shared__ float lg[4][NTAGS];

    float lm = (float)masks[b * SS + tid];
    #pragma unroll
    for (int o = 32; o; o >>= 1) lm += __shfl_xor(lm, o);
    if ((tid & 63) == 0) sred[tid >> 6] = lm;
    __syncthreads();
    float Linv = fast_rcp(sred[0] + sred[1] + sred[2] + sred[3]);

    #pragma unroll
    for (int t = 0; t < 4; ++t) {
        int i = i0 + t;
        float s = 0.f;
        #pragma unroll
        for (int jc = 0; jc < JSPLIT; ++jc)
            s += part[((jc * BB + b) * SS + i) * HH + h];
        float mi = (float)masks[b * SS + i];
        rel_lds[t][h] = fast_tanh(s * Linv * mi);
    }
    __syncthreads();

    int grp = tid >> 6, lane = tid & 63;
    if (lane < NTAGS) {
        float lacc = bo[lane];
        for (int hh = 0; hh < HH; ++hh)
            lacc = fmaf(rel_lds[grp][hh], Wo[hh * NTAGS + lane], lacc);
        lg[grp][lane] = lacc;
    }
    __syncthreads();

    if (tid < 4) {
        float mx = -1e30f;
        #pragma unroll
        for (int t = 0; t < NTAGS; ++t) mx = fmaxf(mx, lg[tid][t]);
        float ex[NTAGS], sum = 0.f;
        #pragma unroll
        for (int t = 0; t < NTAGS; ++t) { ex[t] = __expf(lg[tid][t] - mx); sum += ex[t]; }
        float si = fast_rcp(sum);
        int i = i0 + tid;
        #pragma unroll
        for (int t = 0; t < NTAGS; ++t)
            out[(b * SS + i) * NTAGS + t] = ex[t] * si;
    }
}

extern "C" void kernel_launch(void* const* d_in, const int* in_sizes, int n_in,
                              void* d_out, int out_size, void* d_ws, size_t ws_size,
                              hipStream_t stream) {
    const int*   tokens     = (const int*)d_in[0];
    const int*   masks      = (const int*)d_in[1];
    const float* char_emb   = (const float*)d_in[2];
    const float* bigram_emb = (const float*)d_in[3];
    const float* conv1_w    = (const float*)d_in[4];
    const float* conv1_b    = (const float*)d_in[5];
    const float* conv3_w    = (const float*)d_in[6];
    const float* conv3_b    = (const float*)d_in[7];
    const float* conv5_w    = (const float*)d_in[8];
    const float* conv5_b    = (const float*)d_in[9];
    const float* W0         = (const float*)d_in[10];
    const float* b0         = (const float*)d_in[11];
    const float* W1         = (const float*)d_in[12];
    const float* b1         = (const float*)d_in[13];
    const float* Wo         = (const float*)d_in[14];
    const float* bo         = (const float*)d_in[15];
    float* out = (float*)d_out;

    char* p = (char*)d_ws;
    __hip_bfloat16* xbf    = (__hip_bfloat16*)p;  p += BB * SPAD * EMBED * 2;   // 1.06 MB
    __hip_bfloat16* WcombT = (__hip_bfloat16*)p;  p += 768 * 1280 * 2;          // 1.97 MB
    __hip_bfloat16* W01T   = (__hip_bfloat16*)p;  p += 512 * 256 * 2;           // 0.26 MB
    __hip_bfloat16* cbf    = (__hip_bfloat16*)p;  p += 2048 * 256 * 2;          // 1.05 MB
    float* c   = (float*)p;  p += 2048 * 256 * 4;                               // 2.1 MB
    float* g0n = (float*)p;  p += 2048 * 256 * 4;
    float* g1n = (float*)p;  p += 2048 * 256 * 4;
    float* part = (float*)p; p += JSPLIT * 2048 * 256 * 4;                      // 8.4 MB; total ~19 MB

    embed_pack_kernel<<<BB * SPAD + 1280, 256, 0, stream>>>(
        tokens, char_emb, bigram_emb, conv1_w, conv3_w, conv5_w, W0, W1,
        xbf, WcombT, W01T);
    conv_mfma_fused<<<512, 256, 0, stream>>>(xbf, WcombT, conv1_b, conv3_b,
                                             conv5_b, c, cbf);
    gemm_g_mfma_kernel<<<256, 256, 0, stream>>>(cbf, W01T, b0, b1, g0n, g1n);
    relation_part_kernel<<<JSPLIT * BB * (SS / ITP), 256, 0, stream>>>(
        c, g0n, g1n, masks, part);
    relation_final_kernel<<<BB * (SS / 4), 256, 0, stream>>>(part, masks, Wo, bo, out);
}

// Round 4
// 90.182 us; speedup vs baseline: 2.0691x; 1.1163x over previous
//
#include <hip/hip_runtime.h>
#include <hip/hip_bf16.h>

#define BB 8
#define SS 256
#define CHAR_E 128
#define BI_E 64
#define EMBED 256
#define HH 256
#define NTAGS 17
#define SPAD 260   // S + 2 zero-pad rows each side
#define JSPLIT 16
#define ITP 16     // i-rows per relation_part block
#define NLOG2E -1.4426950408889634f

typedef __attribute__((ext_vector_type(8))) short short8;
typedef __attribute__((ext_vector_type(4))) float f32x4;
#define MFMA16(a, b, c) __builtin_amdgcn_mfma_f32_16x16x32_bf16(a, b, c, 0, 0, 0)

__device__ __forceinline__ float fast_rcp(float x) {
    return __builtin_amdgcn_rcpf(x);
}
__device__ __forceinline__ float fast_exp2(float x) {
    return __builtin_amdgcn_exp2f(x);
}
__device__ __forceinline__ float fast_tanh(float x) {
    float e = __expf(2.0f * x);
    return 1.0f - 2.0f * fast_rcp(e + 1.0f);
}

// ---- fused: embedding gather -> xbf, weight packing -> WcombT/W01T ---------
// WcombT interleaved layout: col n = (h>>4)*48 + scale*16 + (h&15);
// rows kk = tap*256 + e. scale 0: conv5 taps 0..4; 1: conv3 taps 1..3; 2: conv1 tap 2.
__global__ __launch_bounds__(256) void embed_pack_kernel(
        const int* __restrict__ tokens,
        const float* __restrict__ char_emb,
        const float* __restrict__ bigram_emb,
        const float* __restrict__ w1, const float* __restrict__ w3,
        const float* __restrict__ w5,
        const float* __restrict__ W0, const float* __restrict__ W1mat,
        __hip_bfloat16* __restrict__ xbf,
        __hip_bfloat16* __restrict__ WcombT,
        __hip_bfloat16* __restrict__ W01T) {
    int blk = blockIdx.x;
    int t = threadIdx.x;
    if (blk < BB * SPAD) {
        int b = blk / SPAD, r = blk % SPAD;
        float v = 0.0f;
        if (r >= 2 && r < SS + 2) {
            int s = r - 2;
            const int* tk = tokens + (b * SS + s) * 3;
            if (t < CHAR_E)              v = char_emb[tk[0] * CHAR_E + t];
            else if (t < CHAR_E + BI_E)  v = bigram_emb[tk[1] * BI_E + (t - CHAR_E)];
            else                         v = bigram_emb[tk[2] * BI_E + (t - CHAR_E - BI_E)];
        }
        xbf[blk * EMBED + t] = __float2bfloat16(v);
    } else {
        int pb = blk - BB * SPAD;        // 0..1279
        if (pb < 768) {
            int n = pb;
            int hc = n / 48, w16 = n % 48;
            int scale = w16 >> 4, hl = w16 & 15;
            int h = hc * 16 + hl;
            for (int kk = t; kk < 1280; kk += 256) {
                int tap = kk >> 8, e = kk & 255;
                float v = 0.f;
                if (scale == 0)      v = w5[(tap * EMBED + e) * HH + h];
                else if (scale == 1) { if (tap >= 1 && tap <= 3) v = w3[((tap - 1) * EMBED + e) * HH + h]; }
                else                 { if (tap == 2) v = w1[e * HH + h]; }
                WcombT[n * 1280 + kk] = __float2bfloat16(v);
            }
        } else {
            int n = pb - 768;            // 0..511
            float v = (n < 256) ? W0[t * HH + n] : W1mat[t * HH + (n - 256)];
            W01T[n * 256 + t] = __float2bfloat16(v);
        }
    }
}

// ---- conv as MFMA GEMM (M=2048,K=1280,N=768) with fused tanh+max epilogue --
__global__ __launch_bounds__(256) void conv_mfma_fused(
        const __hip_bfloat16* __restrict__ xbf,
        const __hip_bfloat16* __restrict__ WcombT,
        const float* __restrict__ cb1, const float* __restrict__ cb3,
        const float* __restrict__ cb5,
        __hip_bfloat16* __restrict__ cbf) {
    int blk = blockIdx.x;            // 64 m-tiles * 8 h-groups = 512
    int mt = blk >> 3, hg = blk & 7;
    int tid = threadIdx.x, w = tid >> 6, lane = tid & 63;
    int wm = w >> 1, wh = w & 1;
    int fr = lane & 15, fq = lane >> 4;
    int row0 = mt * 32 + wm * 16;
    int hc = hg * 2 + wh;            // h-chunk 0..15

    int i = row0 + fr;
    int b = i >> 8, s = i & 255;
    const short8* ap = (const short8*)(xbf + (b * SPAD + s) * EMBED + fq * 8);
    const short8* bp0 = (const short8*)(WcombT + (hc * 48 + 0 * 16 + fr) * 1280 + fq * 8);
    const short8* bp1 = (const short8*)(WcombT + (hc * 48 + 1 * 16 + fr) * 1280 + fq * 8);
    const short8* bp2 = (const short8*)(WcombT + (hc * 48 + 2 * 16 + fr) * 1280 + fq * 8);

    f32x4 acc[3] = {};
    #pragma unroll 4
    for (int ks = 0; ks < 40; ++ks) {
        short8 a = ap[ks * 4];
        acc[0] = MFMA16(a, bp0[ks * 4], acc[0]);
        acc[1] = MFMA16(a, bp1[ks * 4], acc[1]);
        acc[2] = MFMA16(a, bp2[ks * 4], acc[2]);
    }

    int h = hc * 16 + fr;
    float bb5 = cb5[h], bb3 = cb3[h], bb1 = cb1[h];
    #pragma unroll
    for (int j = 0; j < 4; ++j) {
        int row = row0 + fq * 4 + j;
        float t5 = fast_tanh(acc[0][j] + bb5);
        float t3 = fast_tanh(acc[1][j] + bb3);
        float t1 = fast_tanh(acc[2][j] + bb1);
        float v = fmaxf(t1, fmaxf(t3, t5));
        cbf[row * HH + h] = __float2bfloat16(v);
    }
}

// ---- g0/g1 GEMM (M=2048,K=256,N=512); stores E = exp2(-log2e*(v+bias)) ----
// so that sigmoid(g0+g1) = rcp(1 + E0*E1)  (exp factorization).
__global__ __launch_bounds__(256) void gemm_g_mfma_kernel(
        const __hip_bfloat16* __restrict__ cbf,
        const __hip_bfloat16* __restrict__ W01T,
        const float* __restrict__ b0, const float* __restrict__ b1v,
        float* __restrict__ E0, float* __restrict__ E1) {
    int blk = blockIdx.x;            // 32 m-tiles * 8 n-tiles = 256
    int by = blk / 8, bx = blk % 8;
    int tid = threadIdx.x;
    int w = tid >> 6, lane = tid & 63;
    int wr = w >> 1, wc = w & 1;
    int m0 = by * 64 + wr * 32;
    int n0 = bx * 64 + wc * 32;
    int fr = lane & 15, fq = lane >> 4;

    const short8* aptr[2];
    const short8* bptr[2];
    #pragma unroll
    for (int m = 0; m < 2; ++m)
        aptr[m] = (const short8*)(cbf + (m0 + m * 16 + fr) * HH + fq * 8);
    #pragma unroll
    for (int n = 0; n < 2; ++n)
        bptr[n] = (const short8*)(W01T + (n0 + n * 16 + fr) * HH + fq * 8);

    f32x4 acc[2][2] = {};
    #pragma unroll
    for (int ks = 0; ks < 8; ++ks) {
        short8 a0 = aptr[0][ks * 4];
        short8 a1 = aptr[1][ks * 4];
        short8 b0f = bptr[0][ks * 4];
        short8 b1f = bptr[1][ks * 4];
        acc[0][0] = MFMA16(a0, b0f, acc[0][0]);
        acc[0][1] = MFMA16(a0, b1f, acc[0][1]);
        acc[1][0] = MFMA16(a1, b0f, acc[1][0]);
        acc[1][1] = MFMA16(a1, b1f, acc[1][1]);
    }
    #pragma unroll
    for (int m = 0; m < 2; ++m)
        #pragma unroll
        for (int n = 0; n < 2; ++n) {
            int col = n0 + n * 16 + fr;
            float bias = (col < 256) ? b0[col] : b1v[col - 256];
            #pragma unroll
            for (int j = 0; j < 4; ++j) {
                int row = m0 + m * 16 + fq * 4 + j;
                float ev = fast_exp2(NLOG2E * (acc[m][n][j] + bias));
                if (col < 256) E0[row * HH + col] = ev;
                else           E1[row * HH + (col - 256)] = ev;
            }
        }
}

// ---- relation partial: acc over one j-chunk, ITP=16 rows per block ---------
// sigma(g0+g1) = rcp(1 + E0[i,h]*E1[j,h]): 1 trans + 2 VALU per element.
__global__ __launch_bounds__(256) void relation_part_kernel(
        const __hip_bfloat16* __restrict__ cbf, const float* __restrict__ E0,
        const float* __restrict__ E1, const int* __restrict__ masks,
        float* __restrict__ part) {
    int blk = blockIdx.x;            // jc*128 + b*16 + iblk
    int jc = blk >> 7;
    int rem = blk & 127;
    int b = rem >> 4;
    int i0 = (rem & 15) * ITP;
    int h = threadIdx.x;

    float e0t[ITP], acc[ITP];
    #pragma unroll
    for (int t = 0; t < ITP; ++t) {
        e0t[t] = E0[(b * SS + i0 + t) * HH + h];
        acc[t] = 0.f;
    }

    int j0 = jc * (SS / JSPLIT);
    #pragma unroll 2
    for (int jj = 0; jj < SS / JSPLIT; ++jj) {
        int j = j0 + jj;
        float mj = (float)masks[b * SS + j];
        float e1v = E1[(b * SS + j) * HH + h];
        float cv = __bfloat162float(cbf[(b * SS + j) * HH + h]) * mj;
        #pragma unroll
        for (int t = 0; t < ITP; ++t) {
            float sg = fast_rcp(fmaf(e0t[t], e1v, 1.0f));
            acc[t] = fmaf(sg, cv, acc[t]);
        }
    }
    #pragma unroll
    for (int t = 0; t < ITP; ++t)
        part[((jc * BB + b) * SS + i0 + t) * HH + h] = acc[t];
}

// ---- relation final: reduce partials + tanh + projection + softmax ---------
__global__ __launch_bounds__(256) void relation_final_kernel(
        const float* __restrict__ part, const int* __restrict__ masks,
        const float* __restrict__ Wo, const float* __restrict__ bo,
        float* __restrict__ out) {
    int blk = blockIdx.x;            // b*64 + iblk
    int b = blk >> 6;
    int i0 = (blk & 63) * 4;
    int tid = threadIdx.x;
    int h = tid;

    __shared__ float sred[4];
    __shared__ float rel_lds[4][HH];
    __shared__ float lg[4][NTAGS];

    float lm = (float)masks[b * SS + tid];
    #pragma unroll
    for (int o = 32; o; o >>= 1) lm += __shfl_xor(lm, o);
    if ((tid & 63) == 0) sred[tid >> 6] = lm;
    __syncthreads();
    float Linv = fast_rcp(sred[0] + sred[1] + sred[2] + sred[3]);

    #pragma unroll
    for (int t = 0; t < 4; ++t) {
        int i = i0 + t;
        float s = 0.f;
        #pragma unroll
        for (int jc = 0; jc < JSPLIT; ++jc)
            s += part[((jc * BB + b) * SS + i) * HH + h];
        float mi = (float)masks[b * SS + i];
        rel_lds[t][h] = fast_tanh(s * Linv * mi);
    }
    __syncthreads();

    int grp = tid >> 6, lane = tid & 63;
    if (lane < NTAGS) {
        float lacc = bo[lane];
        for (int hh = 0; hh < HH; ++hh)
            lacc = fmaf(rel_lds[grp][hh], Wo[hh * NTAGS + lane], lacc);
        lg[grp][lane] = lacc;
    }
    __syncthreads();

    if (tid < 4) {
        float mx = -1e30f;
        #pragma unroll
        for (int t = 0; t < NTAGS; ++t) mx = fmaxf(mx, lg[tid][t]);
        float ex[NTAGS], sum = 0.f;
        #pragma unroll
        for (int t = 0; t < NTAGS; ++t) { ex[t] = __expf(lg[tid][t] - mx); sum += ex[t]; }
        float si = fast_rcp(sum);
        int i = i0 + tid;
        #pragma unroll
        for (int t = 0; t < NTAGS; ++t)
            out[(b * SS + i) * NTAGS + t] = ex[t] * si;
    }
}

extern "C" void kernel_launch(void* const* d_in, const int* in_sizes, int n_in,
                              void* d_out, int out_size, void* d_ws, size_t ws_size,
                              hipStream_t stream) {
    const int*   tokens     = (const int*)d_in[0];
    const int*   masks      = (const int*)d_in[1];
    const float* char_emb   = (const float*)d_in[2];
    const float* bigram_emb = (const float*)d_in[3];
    const float* conv1_w    = (const float*)d_in[4];
    const float* conv1_b    = (const float*)d_in[5];
    const float* conv3_w    = (const float*)d_in[6];
    const float* conv3_b    = (const float*)d_in[7];
    const float* conv5_w    = (const float*)d_in[8];
    const float* conv5_b    = (const float*)d_in[9];
    const float* W0         = (const float*)d_in[10];
    const float* b0         = (const float*)d_in[11];
    const float* W1         = (const float*)d_in[12];
    const float* b1         = (const float*)d_in[13];
    const float* Wo         = (const float*)d_in[14];
    const float* bo         = (const float*)d_in[15];
    float* out = (float*)d_out;

    char* p = (char*)d_ws;
    __hip_bfloat16* xbf    = (__hip_bfloat16*)p;  p += BB * SPAD * EMBED * 2;   // 1.06 MB
    __hip_bfloat16* WcombT = (__hip_bfloat16*)p;  p += 768 * 1280 * 2;          // 1.97 MB
    __hip_bfloat16* W01T   = (__hip_bfloat16*)p;  p += 512 * 256 * 2;           // 0.26 MB
    __hip_bfloat16* cbf    = (__hip_bfloat16*)p;  p += 2048 * 256 * 2;          // 1.05 MB
    float* E0 = (float*)p;  p += 2048 * 256 * 4;                                // 2.1 MB
    float* E1 = (float*)p;  p += 2048 * 256 * 4;                                // 2.1 MB
    float* part = (float*)p; p += (size_t)JSPLIT * 2048 * 256 * 4;              // 33.6 MB

    embed_pack_kernel<<<BB * SPAD + 1280, 256, 0, stream>>>(
        tokens, char_emb, bigram_emb, conv1_w, conv3_w, conv5_w, W0, W1,
        xbf, WcombT, W01T);
    conv_mfma_fused<<<512, 256, 0, stream>>>(xbf, WcombT, conv1_b, conv3_b,
                                             conv5_b, cbf);
    gemm_g_mfma_kernel<<<256, 256, 0, stream>>>(cbf, W01T, b0, b1, E0, E1);
    relation_part_kernel<<<JSPLIT * BB * (SS / ITP), 256, 0, stream>>>(
        cbf, E0, E1, masks, part);
    relation_final_kernel<<<BB * (SS / 4), 256, 0, stream>>>(part, masks, Wo, bo, out);
}